// Round 3
// baseline (576.131 us; speedup 1.0000x reference)
//
#include <hip/hip_runtime.h>
#include <stdint.h>

typedef unsigned short u16;
typedef __bf16 bf16x8 __attribute__((ext_vector_type(8)));
typedef float f32x4 __attribute__((ext_vector_type(4)));
typedef u16 u16x8 __attribute__((ext_vector_type(8)));

__device__ __forceinline__ float b2f(u16 v) {
    union { float f; unsigned int u; } x; x.u = ((unsigned int)v) << 16; return x.f;
}
__device__ __forceinline__ u16 f2b(float f) {
    union { float f; unsigned int u; } x; x.f = f;
    unsigned int r = x.u + 0x7fff + ((x.u >> 16) & 1);
    return (u16)(r >> 16);
}

__device__ __forceinline__ void gll16(const void* g, void* l) {
    __builtin_amdgcn_global_load_lds(
        (const __attribute__((address_space(1))) void*)g,
        (__attribute__((address_space(3))) void*)l,
        16, 0, 0);
}

// fp32x8 -> bf16x8, round-half-up, packed via v_perm_b32.
__device__ __forceinline__ bf16x8 pack8(float4 f0, float4 f1) {
    union { float4 f; uint4 u; } a, b;
    a.f = f0; b.f = f1;
    const unsigned sel = 0x07060302u;   // D = {s0.hi16, s1.hi16}
    union { unsigned u[4]; bf16x8 v; } r;
    r.u[0] = __builtin_amdgcn_perm(a.u.y + 0x8000u, a.u.x + 0x8000u, sel);
    r.u[1] = __builtin_amdgcn_perm(a.u.w + 0x8000u, a.u.z + 0x8000u, sel);
    r.u[2] = __builtin_amdgcn_perm(b.u.y + 0x8000u, b.u.x + 0x8000u, sel);
    r.u[3] = __builtin_amdgcn_perm(b.u.w + 0x8000u, b.u.z + 0x8000u, sel);
    return r.v;
}

// fp32 -> bf16 bulk convert, 8 elems/thread (n must be multiple of 2048).
__global__ __launch_bounds__(256) void cvt_kernel(
    const float* __restrict__ s, u16* __restrict__ d)
{
    const size_t i = ((size_t)blockIdx.x * 256 + threadIdx.x) * 8;
    float4 f0 = *(const float4*)(s + i);
    float4 f1 = *(const float4*)(s + i + 4);
    union { bf16x8 v; u16x8 u; } r;
    r.v = pack8(f0, f1);
    *(u16x8*)(d + i) = r.u;
}

// ===================== 256x256 8-phase GEMM =====================
// C[M,N] = act(A[M,K] * B[N,K]^T + bias[N]), bf16 in, fp32 accum, bf16 out.
// 512 thr = 8 waves (2M x 4N), per-wave 128x64 out via interleaved strips:
//   A-frag mi: tile row (mi%4)*32 + wr*16 (+128 for A1); B-frag ni: ni*64+wc*16.
// LDS: 2 K-tile buffers x 4 half-regions {A0,A1,B0,B1}, each [128 rows][64 k]
// bf16, XOR-chunk-swizzled: phys_chunk = r*8 + (c ^ (r&7)), chunk = 8 bf16.
//
// Schedule per iteration i (tile T0=2i in buf0, T1=2i+1 in buf1), 8 phases.
// CRITICAL sync rule (fixed from the inf-producing version): vmcnt is
// per-wave, and each wave stages only a slice of every region, so a counted
// vmcnt wait must be placed BEFORE a barrier, with the dependent ds_reads
// AFTER that barrier (m201 discipline). Waits live at ph3/ph7 tails only:
//   ph0: read a0<-buf0.A0, b0<-buf0.B0; stage (2i+1).A1;  bar; lgkm0; MFMA; bar
//   ph1: read b1<-buf0.B1;              stage (2i+2).A0;  bar; lgkm0; MFMA; bar
//   ph2: read a1<-buf0.A1;              stage (2i+2).B0;  bar; lgkm0; MFMA; bar
//   ph3:                                stage (2i+2).B1;  bar; MFMA; VM6; bar
//   ph4: read a0<-buf1.A0, b0<-buf1.B0; stage (2i+2).A1;  bar; lgkm0; MFMA; bar
//   ph5: read b1<-buf1.B1;              stage (2i+3).A0;  bar; lgkm0; MFMA; bar
//   ph6: read a1<-buf1.A1;              stage (2i+3).B0;  bar; lgkm0; MFMA; bar
//   ph7:                                stage (2i+3).B1;  bar; MFMA; VM6; bar
// Ledger (steady state): entering ph0: 6 in flight = (2i+1).{A0,B0,B1}.
//   ph3's VM6: 14-8 -> completes ALL of tile 2i+1 (buf1) before the barrier;
//   ph4-6 read it after.  ph7's VM6: completes ALL of tile 2i+2 (buf0) for
//   next iter's ph0-2.  Overwrite-safety: each region's last ds_read
//   completes at its phase's lgkm0 < that phase's 2nd barrier < the
//   overwriting DMA's issue (>=1 full phase later for all 8 regions).
// Tail (i = NI-1): all prefetch off except (2i+1).A1; ph3 uses vmcnt(0)
// (with prefetch off, vm6 would leave 3 needed halves in flight).
// Prologue: stage tile0 {A0,B0,B1,A1} then tile1 {A0,B0,B1}; VM6 (completes
// the 8 oldest = tile0); barrier. Requires NI >= 2 (K >= 256).

#define FBAR() do { asm volatile("" ::: "memory"); \
                    __builtin_amdgcn_s_barrier();  \
                    asm volatile("" ::: "memory"); } while (0)
#define WAIT_LGKM0() asm volatile("s_waitcnt lgkmcnt(0)" ::: "memory")
#define WAIT_VM6()   asm volatile("s_waitcnt vmcnt(6)" ::: "memory")
#define WAIT_VM0()   asm volatile("s_waitcnt vmcnt(0)" ::: "memory")

__device__ __forceinline__ void stage_half(
    const u16* __restrict__ Mp, int rowBase, int K, int k0,
    u16* region, int t, int w)
{
#pragma unroll
    for (int it = 0; it < 2; ++it) {
        const int phys = it * 512 + t;        // chunk 0..1023
        const int r = phys >> 3;              // row 0..127
        const int c = (phys & 7) ^ (r & 7);   // swizzled source k-chunk
        gll16(Mp + (size_t)(rowBase + r) * K + (k0 + c * 8),
              (char*)region + (it * 512 + w * 64) * 16);
    }
}

__device__ __forceinline__ void ld_a(const u16* region, int ra, int g0,
                                     bf16x8 (&out)[4][2])
{
#pragma unroll
    for (int mi = 0; mi < 4; ++mi)
#pragma unroll
        for (int s = 0; s < 2; ++s) {
            const int lr = mi * 32 + ra;      // ra = wr*16 + (l&15)
            out[mi][s] = *(const bf16x8*)((const char*)region +
                         (lr * 8 + ((s * 4 + g0) ^ (lr & 7))) * 16);
        }
}

__device__ __forceinline__ void ld_b(const u16* region, int rb, int g0,
                                     bf16x8 (&out)[2][2])
{
#pragma unroll
    for (int ni = 0; ni < 2; ++ni)
#pragma unroll
        for (int s = 0; s < 2; ++s) {
            const int lr = ni * 64 + rb;      // rb = wc*16 + (l&15)
            out[ni][s] = *(const bf16x8*)((const char*)region +
                         (lr * 8 + ((s * 4 + g0) ^ (lr & 7))) * 16);
        }
}

template <int MO, int NO>
__device__ __forceinline__ void mfma_quad(const bf16x8 (&af)[4][2],
                                          const bf16x8 (&bf)[2][2],
                                          f32x4 (&acc)[8][4])
{
    __builtin_amdgcn_s_setprio(1);
#pragma unroll
    for (int mi = 0; mi < 4; ++mi)
#pragma unroll
        for (int ni = 0; ni < 2; ++ni)
#pragma unroll
            for (int s = 0; s < 2; ++s)
                acc[MO + mi][NO + ni] = __builtin_amdgcn_mfma_f32_16x16x32_bf16(
                    af[mi][s], bf[ni][s], acc[MO + mi][NO + ni], 0, 0, 0);
    __builtin_amdgcn_s_setprio(0);
}

template <bool RELU>
__global__ __launch_bounds__(512, 2) void gemm256(
    const u16* __restrict__ A, const u16* __restrict__ Bw,
    const float* __restrict__ bias, u16* __restrict__ C,
    int M, int N, int K)
{
    (void)M;
    __shared__ alignas(16) u16 L[2][4][8192];  // [buf][A0,A1,B0,B1][128*64]

    const int t = threadIdx.x;
    const int l = t & 63;
    const int w = t >> 6;
    const int wr = w >> 2;    // 0..1
    const int wc = w & 3;     // 0..3

    // bijective XCD swizzle (all grids here have nwg % 8 == 0)
    const int gx = gridDim.x;
    const int nwg = gx * gridDim.y;
    const int orig = blockIdx.y * gx + blockIdx.x;
    const int q8 = nwg >> 3, r8 = nwg & 7;
    const int xcd = orig & 7, rem = orig >> 3;
    const int wg = (xcd < r8 ? xcd * (q8 + 1)
                             : r8 * (q8 + 1) + (xcd - r8) * q8) + rem;
    const int mBase = (wg / gx) * 256;
    const int nBase = (wg % gx) * 256;

    const int frow = l & 15;
    const int g0 = l >> 4;
    const int ra = wr * 16 + frow;
    const int rb = wc * 16 + frow;

    f32x4 acc[8][4] = {};
    bf16x8 a0[4][2], a1[4][2], b0[2][2], b1[2][2];

    const int NI = K >> 7;   // K/128; requires K multiple of 128, K >= 256

    // prologue: tile0 -> buf0 (all 4 halves first!), tile1 -> buf1 (3 halves)
    stage_half(A,  mBase,       K, 0,  &L[0][0][0], t, w);
    stage_half(Bw, nBase,       K, 0,  &L[0][2][0], t, w);
    stage_half(Bw, nBase + 128, K, 0,  &L[0][3][0], t, w);
    stage_half(A,  mBase + 128, K, 0,  &L[0][1][0], t, w);
    stage_half(A,  mBase,       K, 64, &L[1][0][0], t, w);
    stage_half(Bw, nBase,       K, 64, &L[1][2][0], t, w);
    stage_half(Bw, nBase + 128, K, 64, &L[1][3][0], t, w);
    WAIT_VM6();          // completes the 8 oldest = all of tile0 (buf0)
    FBAR();              // -> buf0 globally visible before any ph0 read

    for (int i = 0; i < NI; ++i) {
        const bool nl = (i + 1 < NI);
        const int kT1 = (2 * i + 1) << 6;
        const int kT2 = (2 * i + 2) << 6;
        const int kT3 = (2 * i + 3) << 6;

        // ---- phase 0 ----
        ld_a(&L[0][0][0], ra, g0, a0);
        ld_b(&L[0][2][0], rb, g0, b0);
        stage_half(A, mBase + 128, K, kT1, &L[1][1][0], t, w);    // (2i+1).A1
        FBAR();
        WAIT_LGKM0();
        mfma_quad<0, 0>(a0, b0, acc);
        FBAR();

        // ---- phase 1 ----
        ld_b(&L[0][3][0], rb, g0, b1);
        if (nl) stage_half(A, mBase, K, kT2, &L[0][0][0], t, w);  // (2i+2).A0
        FBAR();
        WAIT_LGKM0();
        mfma_quad<0, 2>(a0, b1, acc);
        FBAR();

        // ---- phase 2 ----
        ld_a(&L[0][1][0], ra, g0, a1);
        if (nl) stage_half(Bw, nBase, K, kT2, &L[0][2][0], t, w); // (2i+2).B0
        FBAR();
        WAIT_LGKM0();
        mfma_quad<4, 0>(a1, b0, acc);
        FBAR();

        // ---- phase 3 ----  (wait BEFORE barrier; ph4 reads AFTER it)
        if (nl) stage_half(Bw, nBase + 128, K, kT2, &L[0][3][0], t, w); // .B1
        FBAR();
        mfma_quad<4, 2>(a1, b1, acc);
        if (nl) { WAIT_VM6(); } else { WAIT_VM0(); }
        FBAR();

        // ---- phase 4 ----
        ld_a(&L[1][0][0], ra, g0, a0);
        ld_b(&L[1][2][0], rb, g0, b0);
        if (nl) stage_half(A, mBase + 128, K, kT2, &L[0][1][0], t, w); // .A1
        FBAR();
        WAIT_LGKM0();
        mfma_quad<0, 0>(a0, b0, acc);
        FBAR();

        // ---- phase 5 ----
        ld_b(&L[1][3][0], rb, g0, b1);
        if (nl) stage_half(A, mBase, K, kT3, &L[1][0][0], t, w);  // (2i+3).A0
        FBAR();
        WAIT_LGKM0();
        mfma_quad<0, 2>(a0, b1, acc);
        FBAR();

        // ---- phase 6 ----
        ld_a(&L[1][1][0], ra, g0, a1);
        if (nl) stage_half(Bw, nBase, K, kT3, &L[1][2][0], t, w); // (2i+3).B0
        FBAR();
        WAIT_LGKM0();
        mfma_quad<4, 0>(a1, b0, acc);
        FBAR();

        // ---- phase 7 ----  (wait BEFORE barrier; next ph0 reads AFTER it)
        if (nl) stage_half(Bw, nBase + 128, K, kT3, &L[1][3][0], t, w); // .B1
        FBAR();
        mfma_quad<4, 2>(a1, b1, acc);
        if (nl) { WAIT_VM6(); }
        FBAR();
    }

    // epilogue: C/D layout col = l&15, row = (l>>4)*4 + reg
    const int rq = (l >> 4) * 4;
#pragma unroll
    for (int ni = 0; ni < 4; ++ni) {
        const int col = nBase + ni * 64 + wc * 16 + (l & 15);
        const float bv = bias[col];
#pragma unroll
        for (int mi = 0; mi < 8; ++mi) {
            const int row = mBase + mi * 32 + wr * 16 + rq;
#pragma unroll
            for (int i2 = 0; i2 < 4; ++i2) {
                float v = acc[mi][ni][i2] + bv;
                if (RELU) v = fmaxf(v, 0.0f);
                C[(size_t)(row + i2) * N + col] = f2b(v);
            }
        }
    }
}

// GRU elementwise: r = sig(ir+hr); z = sig(iz+hz); n = tanh(inn + r*hn);
// h = (1-z)*n + z*h_prev. gi/gh bf16, hprev fp32; writes h fp32 (output) and
// bf16 copy (for the q GEMM). 8 elems/thread.
__global__ __launch_bounds__(256) void gru_kernel(
    const u16* __restrict__ gi, const u16* __restrict__ gh,
    const float* __restrict__ hprev, float* __restrict__ houtf,
    u16* __restrict__ houtb, int H)
{
    const size_t idx = ((size_t)blockIdx.x * 256 + threadIdx.x) * 8;
    const size_t b = idx / H;
    const size_t j = idx - b * H;
    const size_t g0 = b * (size_t)(3 * H) + j;

    u16x8 vir = *(const u16x8*)&gi[g0];
    u16x8 viz = *(const u16x8*)&gi[g0 + H];
    u16x8 vin = *(const u16x8*)&gi[g0 + 2 * H];
    u16x8 vhr = *(const u16x8*)&gh[g0];
    u16x8 vhz = *(const u16x8*)&gh[g0 + H];
    u16x8 vhn = *(const u16x8*)&gh[g0 + 2 * H];
    float4 hp0 = *(const float4*)&hprev[idx];
    float4 hp1 = *(const float4*)&hprev[idx + 4];
    float hp[8] = {hp0.x, hp0.y, hp0.z, hp0.w, hp1.x, hp1.y, hp1.z, hp1.w};
    float ho[8];
    u16x8 ob;
#pragma unroll
    for (int i = 0; i < 8; ++i) {
        float r = 1.f / (1.f + expf(-(b2f(vir[i]) + b2f(vhr[i]))));
        float z = 1.f / (1.f + expf(-(b2f(viz[i]) + b2f(vhz[i]))));
        float n = tanhf(b2f(vin[i]) + r * b2f(vhn[i]));
        float h = (1.f - z) * n + z * hp[i];
        ho[i] = h;
        ob[i] = f2b(h);
    }
    *(float4*)&houtf[idx]     = make_float4(ho[0], ho[1], ho[2], ho[3]);
    *(float4*)&houtf[idx + 4] = make_float4(ho[4], ho[5], ho[6], ho[7]);
    *(u16x8*)&houtb[idx] = ob;
}

// Decode: per row i of q[4096,4096] (bf16):
//   out[2i,  j] = max(q[i, j..j+63])                 (windows, j<64)
//   out[2i+1,j] = max over m with m % 64 == (j-1)%64 (strided residue class)
__global__ __launch_bounds__(256) void decode_kernel(
    const u16* __restrict__ q, float* __restrict__ out)
{
    __shared__ float s[4096];
    const int row = blockIdx.x;
    const int t = threadIdx.x;
    const size_t base = (size_t)row * 4096;
#pragma unroll
    for (int i = 0; i < 16; ++i) {
        int j = t + i * 256;
        s[j] = b2f(q[base + j]);
    }
    __syncthreads();
    if (t < 64) {
        float m = -INFINITY;
#pragma unroll 8
        for (int k = 0; k < 64; ++k) m = fmaxf(m, s[t + k]);
        out[(size_t)(2 * row) * 64 + t] = m;
    } else if (t < 128) {
        const int rr = t - 64;
        float m = -INFINITY;
#pragma unroll 8
        for (int k = 0; k < 64; ++k) m = fmaxf(m, s[rr + 64 * k]);
        const int j = (rr + 1) & 63;   // residue rr corresponds to output col j
        out[(size_t)(2 * row + 1) * 64 + j] = m;
    }
}

extern "C" void kernel_launch(void* const* d_in, const int* in_sizes, int n_in,
                              void* d_out, int out_size, void* d_ws, size_t ws_size,
                              hipStream_t stream) {
    constexpr int Bn = 4096, IN = 1024, H = 2048, A = 64, A2 = A * A;
    constexpr size_t BH  = (size_t)Bn * H;        //  8,388,608
    constexpr size_t H3H = (size_t)3 * H * H;     // 12,582,912
    constexpr size_t HIN = (size_t)H * IN;        //  2,097,152
    constexpr size_t BIN = (size_t)Bn * IN;       //  4,194,304
    constexpr size_t A2H = (size_t)A2 * H;        //  8,388,608
    constexpr size_t B3H = (size_t)Bn * 3 * H;    // 25,165,824
    constexpr size_t BA2 = (size_t)Bn * A2;       // 16,777,216

    const float* inputs = (const float*)d_in[0];
    const float* h0     = (const float*)d_in[1];
    const float* W1     = (const float*)d_in[2];
    const float* b1     = (const float*)d_in[3];
    const float* Wih    = (const float*)d_in[4];
    const float* Whh    = (const float*)d_in[5];
    const float* bih    = (const float*)d_in[6];
    const float* bhh    = (const float*)d_in[7];
    const float* W2     = (const float*)d_in[8];
    const float* b2     = (const float*)d_in[9];

    float* out  = (float*)d_out;                 // [2B, A] fp32
    float* hout = out + (size_t)2 * Bn * A;      // [B, H] fp32 (output 1)

    // ws layout (u16 elems), phase-overlaid — peak ~176 MB:
    u16* wsu  = (u16*)d_ws;
    u16* h0b  = wsu;                  // phase 1: [B,H]
    u16* Whhb = wsu + BH;             // phase 1: [3H,H]   (region A = BH+H3H)
    u16* Wihb = wsu;                  // phase 2: [3H,H]   (overlays h0b/Whhb)
    u16* W1b  = wsu + H3H;            // phase 2: [H,IN]
    u16* inb  = wsu + H3H + HIN;      // phase 2: [B,IN]   (18.9M <= 21.0M ok)
    u16* x    = wsu + BH + H3H;       // [B,H]
    u16* gi   = x + BH;               // [B,3H]
    u16* gh   = gi + B3H;             // [B,3H]
    u16* hbf  = gh + B3H;             // [B,H]
    u16* q    = gi;                   // [B,A2] reuses gi after GRU
    u16* W2b  = gi + BA2;             // [A2,H] in gi tail (exactly fills it)

    dim3 blk(256);
    dim3 gblk(512);
    // phase 1: gh = h0 @ Whh^T + bhh
    cvt_kernel<<<dim3(BH  / 2048), blk, 0, stream>>>(h0,  h0b);
    cvt_kernel<<<dim3(H3H / 2048), blk, 0, stream>>>(Whh, Whhb);
    gemm256<false><<<dim3(3 * H / 256, Bn / 256), gblk, 0, stream>>>(
        h0b, Whhb, bhh, gh, Bn, 3 * H, H);
    // phase 2: x = relu(inputs @ W1^T + b1); gi = x @ Wih^T + bih
    cvt_kernel<<<dim3(HIN / 2048), blk, 0, stream>>>(W1, W1b);
    cvt_kernel<<<dim3(BIN / 2048), blk, 0, stream>>>(inputs, inb);
    cvt_kernel<<<dim3(H3H / 2048), blk, 0, stream>>>(Wih, Wihb);
    gemm256<true><<<dim3(H / 256, Bn / 256), gblk, 0, stream>>>(
        inb, W1b, b1, x, Bn, H, IN);
    gemm256<false><<<dim3(3 * H / 256, Bn / 256), gblk, 0, stream>>>(
        x, Wihb, bih, gi, Bn, 3 * H, H);
    // GRU -> h (fp32 into d_out, bf16 copy into ws); frees gi
    gru_kernel<<<dim3((Bn * H / 8) / 256), blk, 0, stream>>>(
        gi, gh, h0, hout, hbf, H);
    // phase 3: q = h @ W2^T + b2 (W2b lives in gi tail, q in gi head)
    cvt_kernel<<<dim3(A2H / 2048), blk, 0, stream>>>(W2, W2b);
    gemm256<false><<<dim3(A2 / 256, Bn / 256), gblk, 0, stream>>>(
        hbf, W2b, b2, q, Bn, A2, H);
    // decode maxes -> out (fp32)
    decode_kernel<<<dim3(Bn), blk, 0, stream>>>(q, out);
}

// Round 4
// 530.531 us; speedup vs baseline: 1.0860x; 1.0860x over previous
//
#include <hip/hip_runtime.h>
#include <stdint.h>

typedef unsigned short u16;
typedef __bf16 bf16x8 __attribute__((ext_vector_type(8)));
typedef float f32x4 __attribute__((ext_vector_type(4)));
typedef u16 u16x8 __attribute__((ext_vector_type(8)));

__device__ __forceinline__ float b2f(u16 v) {
    union { float f; unsigned int u; } x; x.u = ((unsigned int)v) << 16; return x.f;
}
__device__ __forceinline__ u16 f2b(float f) {
    union { float f; unsigned int u; } x; x.f = f;
    unsigned int r = x.u + 0x7fff + ((x.u >> 16) & 1);
    return (u16)(r >> 16);
}

__device__ __forceinline__ void gll16(const void* g, void* l) {
    __builtin_amdgcn_global_load_lds(
        (const __attribute__((address_space(1))) void*)g,
        (__attribute__((address_space(3))) void*)l,
        16, 0, 0);
}

// fp32x8 -> bf16x8, round-half-up, packed via v_perm_b32.
__device__ __forceinline__ bf16x8 pack8(float4 f0, float4 f1) {
    union { float4 f; uint4 u; } a, b;
    a.f = f0; b.f = f1;
    const unsigned sel = 0x07060302u;   // D = {s0.hi16, s1.hi16}
    union { unsigned u[4]; bf16x8 v; } r;
    r.u[0] = __builtin_amdgcn_perm(a.u.y + 0x8000u, a.u.x + 0x8000u, sel);
    r.u[1] = __builtin_amdgcn_perm(a.u.w + 0x8000u, a.u.z + 0x8000u, sel);
    r.u[2] = __builtin_amdgcn_perm(b.u.y + 0x8000u, b.u.x + 0x8000u, sel);
    r.u[3] = __builtin_amdgcn_perm(b.u.w + 0x8000u, b.u.z + 0x8000u, sel);
    return r.v;
}

// fp32 -> bf16 bulk convert, 8 elems/thread (n must be multiple of 2048).
__global__ __launch_bounds__(256) void cvt_kernel(
    const float* __restrict__ s, u16* __restrict__ d)
{
    const size_t i = ((size_t)blockIdx.x * 256 + threadIdx.x) * 8;
    float4 f0 = *(const float4*)(s + i);
    float4 f1 = *(const float4*)(s + i + 4);
    union { bf16x8 v; u16x8 u; } r;
    r.v = pack8(f0, f1);
    *(u16x8*)(d + i) = r.u;
}

// ===================== 256x256 8-phase GEMM body =====================
// C[M,N] = act(A[M,K] * B[N,K]^T + bias[N]), bf16 in, fp32 accum, bf16 out.
// 512 thr = 8 waves (2M x 4N), per-wave 128x64 out via interleaved strips.
// LDS: 2 K-tile buffers x 4 half-regions {A0,A1,B0,B1}, each [128 r][64 k]
// bf16, XOR-chunk-swizzled: phys_chunk = r*8 + (c ^ (r&7)), chunk = 8 bf16.
// Sync discipline (m201): counted vmcnt waits sit BEFORE a barrier with the
// dependent ds_reads AFTER it (vmcnt is per-wave; each wave stages only a
// slice of every region). vm6 at ph3/ph7 completes the full next tile.
// XCD partition: 2x4 XCD rectangles, each (gy/2)x(gx/4) tiles -> per-XCD
// concurrent L2 footprint ~12MB (vs 26MB for row-bands). Needs gy%2, gx%4.

#define FBAR() do { asm volatile("" ::: "memory"); \
                    __builtin_amdgcn_s_barrier();  \
                    asm volatile("" ::: "memory"); } while (0)
#define WAIT_LGKM0() asm volatile("s_waitcnt lgkmcnt(0)" ::: "memory")
#define WAIT_VM6()   asm volatile("s_waitcnt vmcnt(6)" ::: "memory")
#define WAIT_VM0()   asm volatile("s_waitcnt vmcnt(0)" ::: "memory")

__device__ __forceinline__ void stage_half(
    const u16* __restrict__ Mp, int rowBase, int K, int k0,
    u16* region, int t, int w)
{
#pragma unroll
    for (int it = 0; it < 2; ++it) {
        const int phys = it * 512 + t;        // chunk 0..1023
        const int r = phys >> 3;              // row 0..127
        const int c = (phys & 7) ^ (r & 7);   // swizzled source k-chunk
        gll16(Mp + (size_t)(rowBase + r) * K + (k0 + c * 8),
              (char*)region + (it * 512 + w * 64) * 16);
    }
}

__device__ __forceinline__ void ld_a(const u16* region, int ra, int g0,
                                     bf16x8 (&out)[4][2])
{
#pragma unroll
    for (int mi = 0; mi < 4; ++mi)
#pragma unroll
        for (int s = 0; s < 2; ++s) {
            const int lr = mi * 32 + ra;      // ra = wr*16 + (l&15)
            out[mi][s] = *(const bf16x8*)((const char*)region +
                         (lr * 8 + ((s * 4 + g0) ^ (lr & 7))) * 16);
        }
}

__device__ __forceinline__ void ld_b(const u16* region, int rb, int g0,
                                     bf16x8 (&out)[2][2])
{
#pragma unroll
    for (int ni = 0; ni < 2; ++ni)
#pragma unroll
        for (int s = 0; s < 2; ++s) {
            const int lr = ni * 64 + rb;      // rb = wc*16 + (l&15)
            out[ni][s] = *(const bf16x8*)((const char*)region +
                         (lr * 8 + ((s * 4 + g0) ^ (lr & 7))) * 16);
        }
}

template <int MO, int NO>
__device__ __forceinline__ void mfma_quad(const bf16x8 (&af)[4][2],
                                          const bf16x8 (&bf)[2][2],
                                          f32x4 (&acc)[8][4])
{
    __builtin_amdgcn_s_setprio(1);
#pragma unroll
    for (int mi = 0; mi < 4; ++mi)
#pragma unroll
        for (int ni = 0; ni < 2; ++ni)
#pragma unroll
            for (int s = 0; s < 2; ++s)
                acc[MO + mi][NO + ni] = __builtin_amdgcn_mfma_f32_16x16x32_bf16(
                    af[mi][s], bf[ni][s], acc[MO + mi][NO + ni], 0, 0, 0);
    __builtin_amdgcn_s_setprio(0);
}

template <bool RELU>
__device__ __forceinline__ void gemm_body(
    const u16* __restrict__ A, const u16* __restrict__ Bw,
    const float* __restrict__ bias, u16* __restrict__ C,
    int N, int K, int gy, int gx, int bid)
{
    __shared__ alignas(16) u16 L[2][4][8192];  // [buf][A0,A1,B0,B1][128*64]

    const int t = threadIdx.x;
    const int l = t & 63;
    const int w = t >> 6;
    const int wr = w >> 2;    // 0..1
    const int wc = w & 3;     // 0..3

    // 2x4 rectangular XCD partition (bijective; needs gy%2==0, gx%4==0,
    // and gy*gx % 8 == 0). bid round-robins over XCDs (bid&7).
    const int xcd = bid & 7, rem = bid >> 3;
    const int rrows = gy >> 1, rcols = gx >> 2;
    const int lr_ = rem / rcols, lc_ = rem % rcols;
    const int mBase = ((xcd >> 2) * rrows + lr_) * 256;
    const int nBase = ((xcd & 3) * rcols + lc_) * 256;

    const int frow = l & 15;
    const int g0 = l >> 4;
    const int ra = wr * 16 + frow;
    const int rb = wc * 16 + frow;

    f32x4 acc[8][4] = {};
    bf16x8 a0[4][2], a1[4][2], b0[2][2], b1[2][2];

    const int NI = K >> 7;   // K/128; requires K multiple of 128, K >= 256

    // prologue: tile0 -> buf0 (all 4 halves first!), tile1 -> buf1 (3 halves)
    stage_half(A,  mBase,       K, 0,  &L[0][0][0], t, w);
    stage_half(Bw, nBase,       K, 0,  &L[0][2][0], t, w);
    stage_half(Bw, nBase + 128, K, 0,  &L[0][3][0], t, w);
    stage_half(A,  mBase + 128, K, 0,  &L[0][1][0], t, w);
    stage_half(A,  mBase,       K, 64, &L[1][0][0], t, w);
    stage_half(Bw, nBase,       K, 64, &L[1][2][0], t, w);
    stage_half(Bw, nBase + 128, K, 64, &L[1][3][0], t, w);
    WAIT_VM6();          // completes the 8 oldest = all of tile0 (buf0)
    FBAR();              // -> buf0 globally visible before any ph0 read

    for (int i = 0; i < NI; ++i) {
        const bool nl = (i + 1 < NI);
        const int kT1 = (2 * i + 1) << 6;
        const int kT2 = (2 * i + 2) << 6;
        const int kT3 = (2 * i + 3) << 6;

        // ---- phase 0 ----
        ld_a(&L[0][0][0], ra, g0, a0);
        ld_b(&L[0][2][0], rb, g0, b0);
        stage_half(A, mBase + 128, K, kT1, &L[1][1][0], t, w);    // (2i+1).A1
        FBAR();
        WAIT_LGKM0();
        mfma_quad<0, 0>(a0, b0, acc);
        FBAR();

        // ---- phase 1 ----
        ld_b(&L[0][3][0], rb, g0, b1);
        if (nl) stage_half(A, mBase, K, kT2, &L[0][0][0], t, w);  // (2i+2).A0
        FBAR();
        WAIT_LGKM0();
        mfma_quad<0, 2>(a0, b1, acc);
        FBAR();

        // ---- phase 2 ----
        ld_a(&L[0][1][0], ra, g0, a1);
        if (nl) stage_half(Bw, nBase, K, kT2, &L[0][2][0], t, w); // (2i+2).B0
        FBAR();
        WAIT_LGKM0();
        mfma_quad<4, 0>(a1, b0, acc);
        FBAR();

        // ---- phase 3 ----  (wait BEFORE barrier; ph4 reads AFTER it)
        if (nl) stage_half(Bw, nBase + 128, K, kT2, &L[0][3][0], t, w); // .B1
        FBAR();
        mfma_quad<4, 2>(a1, b1, acc);
        if (nl) { WAIT_VM6(); } else { WAIT_VM0(); }
        FBAR();

        // ---- phase 4 ----
        ld_a(&L[1][0][0], ra, g0, a0);
        ld_b(&L[1][2][0], rb, g0, b0);
        if (nl) stage_half(A, mBase + 128, K, kT2, &L[0][1][0], t, w); // .A1
        FBAR();
        WAIT_LGKM0();
        mfma_quad<0, 0>(a0, b0, acc);
        FBAR();

        // ---- phase 5 ----
        ld_b(&L[1][3][0], rb, g0, b1);
        if (nl) stage_half(A, mBase, K, kT3, &L[1][0][0], t, w);  // (2i+3).A0
        FBAR();
        WAIT_LGKM0();
        mfma_quad<0, 2>(a0, b1, acc);
        FBAR();

        // ---- phase 6 ----
        ld_a(&L[1][1][0], ra, g0, a1);
        if (nl) stage_half(Bw, nBase, K, kT3, &L[1][2][0], t, w); // (2i+3).B0
        FBAR();
        WAIT_LGKM0();
        mfma_quad<4, 0>(a1, b0, acc);
        FBAR();

        // ---- phase 7 ----  (wait BEFORE barrier; next ph0 reads AFTER it)
        if (nl) stage_half(Bw, nBase + 128, K, kT3, &L[1][3][0], t, w); // .B1
        FBAR();
        mfma_quad<4, 2>(a1, b1, acc);
        if (nl) { WAIT_VM6(); }
        FBAR();
    }

    // epilogue: C/D layout col = l&15, row = (l>>4)*4 + reg
    const int rq = (l >> 4) * 4;
#pragma unroll
    for (int ni = 0; ni < 4; ++ni) {
        const int col = nBase + ni * 64 + wc * 16 + (l & 15);
        const float bv = bias[col];
#pragma unroll
        for (int mi = 0; mi < 8; ++mi) {
            const int row = mBase + mi * 32 + wr * 16 + rq;
#pragma unroll
            for (int i2 = 0; i2 < 4; ++i2) {
                float v = acc[mi][ni][i2] + bv;
                if (RELU) v = fmaxf(v, 0.0f);
                C[(size_t)(row + i2) * N + col] = f2b(v);
            }
        }
    }
}

// Standalone GEMM launch (1-D grid of gy*gx blocks).
template <bool RELU>
__global__ __launch_bounds__(512, 2) void gemm256(
    const u16* __restrict__ A, const u16* __restrict__ Bw,
    const float* __restrict__ bias, u16* __restrict__ C,
    int N, int K, int gy, int gx)
{
    gemm_body<RELU>(A, Bw, bias, C, N, K, gy, gx, blockIdx.x);
}

// Heterogeneous launch: blocks [0, gy*gx) run the GEMM; blocks beyond run
// fp32->bf16 cvt segments (4096 elems/block, 512 thr x 8). The cvt work is
// INDEPENDENT of the GEMM (disjoint ws regions) and fills the GEMM's
// half-empty scheduling rounds + a short tail.
__global__ __launch_bounds__(512, 2) void mega_kernel(
    const u16* __restrict__ A, const u16* __restrict__ Bw,
    const float* __restrict__ bias, u16* __restrict__ C,
    int N, int K, int gy, int gx,
    const float* __restrict__ s0, u16* __restrict__ d0, int n0,
    const float* __restrict__ s1, u16* __restrict__ d1, int n1,
    const float* __restrict__ s2, u16* __restrict__ d2, int n2)
{
    const int gemmBlocks = gy * gx;
    const int bid = blockIdx.x;
    if (bid < gemmBlocks) {
        gemm_body<false>(A, Bw, bias, C, N, K, gy, gx, bid);
        return;
    }
    int cb = bid - gemmBlocks;
    const float* s; u16* d;
    if (cb < n0)            { s = s0; d = d0; }
    else if (cb < n0 + n1)  { cb -= n0; s = s1; d = d1; }
    else                    { cb -= n0 + n1; s = s2; d = d2; }
    const size_t i = ((size_t)cb * 512 + threadIdx.x) * 8;
    float4 f0 = *(const float4*)(s + i);
    float4 f1 = *(const float4*)(s + i + 4);
    union { bf16x8 v; u16x8 u; } r;
    r.v = pack8(f0, f1);
    *(u16x8*)(d + i) = r.u;
}

// GRU elementwise: r = sig(ir+hr); z = sig(iz+hz); n = tanh(inn + r*hn);
// h = (1-z)*n + z*h_prev. gi/gh bf16, hprev fp32; writes h fp32 (output) and
// bf16 copy (for the q GEMM). 8 elems/thread.
__global__ __launch_bounds__(256) void gru_kernel(
    const u16* __restrict__ gi, const u16* __restrict__ gh,
    const float* __restrict__ hprev, float* __restrict__ houtf,
    u16* __restrict__ houtb, int H)
{
    const size_t idx = ((size_t)blockIdx.x * 256 + threadIdx.x) * 8;
    const size_t b = idx / H;
    const size_t j = idx - b * H;
    const size_t g0 = b * (size_t)(3 * H) + j;

    u16x8 vir = *(const u16x8*)&gi[g0];
    u16x8 viz = *(const u16x8*)&gi[g0 + H];
    u16x8 vin = *(const u16x8*)&gi[g0 + 2 * H];
    u16x8 vhr = *(const u16x8*)&gh[g0];
    u16x8 vhz = *(const u16x8*)&gh[g0 + H];
    u16x8 vhn = *(const u16x8*)&gh[g0 + 2 * H];
    float4 hp0 = *(const float4*)&hprev[idx];
    float4 hp1 = *(const float4*)&hprev[idx + 4];
    float hp[8] = {hp0.x, hp0.y, hp0.z, hp0.w, hp1.x, hp1.y, hp1.z, hp1.w};
    float ho[8];
    u16x8 ob;
#pragma unroll
    for (int i = 0; i < 8; ++i) {
        float r = 1.f / (1.f + expf(-(b2f(vir[i]) + b2f(vhr[i]))));
        float z = 1.f / (1.f + expf(-(b2f(viz[i]) + b2f(vhz[i]))));
        float n = tanhf(b2f(vin[i]) + r * b2f(vhn[i]));
        float h = (1.f - z) * n + z * hp[i];
        ho[i] = h;
        ob[i] = f2b(h);
    }
    *(float4*)&houtf[idx]     = make_float4(ho[0], ho[1], ho[2], ho[3]);
    *(float4*)&houtf[idx + 4] = make_float4(ho[4], ho[5], ho[6], ho[7]);
    *(u16x8*)&houtb[idx] = ob;
}

// Decode: per row i of q[4096,4096] (bf16):
//   out[2i,  j] = max(q[i, j..j+63])                 (windows, j<64)
//   out[2i+1,j] = max over m with m % 64 == (j-1)%64 (strided residue class)
__global__ __launch_bounds__(256) void decode_kernel(
    const u16* __restrict__ q, float* __restrict__ out)
{
    __shared__ float s[4096];
    const int row = blockIdx.x;
    const int t = threadIdx.x;
    const size_t base = (size_t)row * 4096;
#pragma unroll
    for (int i = 0; i < 16; ++i) {
        int j = t + i * 256;
        s[j] = b2f(q[base + j]);
    }
    __syncthreads();
    if (t < 64) {
        float m = -INFINITY;
#pragma unroll 8
        for (int k = 0; k < 64; ++k) m = fmaxf(m, s[t + k]);
        out[(size_t)(2 * row) * 64 + t] = m;
    } else if (t < 128) {
        const int rr = t - 64;
        float m = -INFINITY;
#pragma unroll 8
        for (int k = 0; k < 64; ++k) m = fmaxf(m, s[rr + 64 * k]);
        const int j = (rr + 1) & 63;   // residue rr corresponds to output col j
        out[(size_t)(2 * row + 1) * 64 + j] = m;
    }
}

extern "C" void kernel_launch(void* const* d_in, const int* in_sizes, int n_in,
                              void* d_out, int out_size, void* d_ws, size_t ws_size,
                              hipStream_t stream) {
    constexpr int Bn = 4096, IN = 1024, H = 2048, A = 64, A2 = A * A;
    constexpr size_t BH  = (size_t)Bn * H;        //  8,388,608
    constexpr size_t H3H = (size_t)3 * H * H;     // 12,582,912
    constexpr size_t HIN = (size_t)H * IN;        //  2,097,152
    constexpr size_t BIN = (size_t)Bn * IN;       //  4,194,304
    constexpr size_t A2H = (size_t)A2 * H;        //  8,388,608
    constexpr size_t B3H = (size_t)Bn * 3 * H;    // 25,165,824

    const float* inputs = (const float*)d_in[0];
    const float* h0     = (const float*)d_in[1];
    const float* W1     = (const float*)d_in[2];
    const float* b1     = (const float*)d_in[3];
    const float* Wih    = (const float*)d_in[4];
    const float* Whh    = (const float*)d_in[5];
    const float* bih    = (const float*)d_in[6];
    const float* bhh    = (const float*)d_in[7];
    const float* W2     = (const float*)d_in[8];
    const float* b2     = (const float*)d_in[9];

    float* out  = (float*)d_out;                 // [2B, A] fp32
    float* hout = out + (size_t)2 * Bn * A;      // [B, H] fp32 (output 1)

    // ws layout (u16 elems), non-overlapping lifetimes — peak 172.0 MB
    // (<= the 176.4 MB footprint already proven on this harness):
    //  r0 [0, B3H):          h0b [0,BH) + Whhb [BH,BH+H3H)  -> gi -> q
    //  r1 [B3H, 2*B3H):      gh
    //  r2 [2*B3H, +H3H):     Wihb  -> hbf (after gi GEMM)
    //  r3..: W1b, inb, xb, W2b
    u16* wsu  = (u16*)d_ws;
    u16* h0b  = wsu;                       // phase 1 only
    u16* Whhb = wsu + BH;                  // phase 1 only
    u16* gi   = wsu;                       // after gh GEMM done
    u16* q    = wsu;                       // after GRU done
    u16* gh   = wsu + B3H;
    u16* Wihb = wsu + 2 * B3H;
    u16* hbf  = wsu + 2 * B3H;             // reuses Wihb after gi GEMM
    u16* W1b  = wsu + 2 * B3H + H3H;
    u16* inb  = W1b + HIN;
    u16* xb   = inb + BIN;
    u16* W2b  = xb + BH;                   // end = 85,983,232 u16 = 172.0 MB

    dim3 blk(256);
    dim3 gblk(512);

    // 1) h0, Whh -> bf16 (needed by the gh GEMM)
    cvt_kernel<<<dim3(BH  / 2048), blk, 0, stream>>>(h0,  h0b);
    cvt_kernel<<<dim3(H3H / 2048), blk, 0, stream>>>(Whh, Whhb);

    // 2) gh = h0 @ Whh^T + bhh  FUSED with phase-2 cvts (W1, inputs, Wih):
    //    384 GEMM blocks (2 rounds at 1 blk/CU) + 4608 cvt blocks that fill
    //    the half-empty round 2 and tail.
    mega_kernel<<<dim3(16 * 24 + 512 + 1024 + 3072), gblk, 0, stream>>>(
        h0b, Whhb, bhh, gh, 3 * H, H, 16, 24,
        W1,     W1b,  (int)(HIN / 4096),
        inputs, inb,  (int)(BIN / 4096),
        Wih,    Wihb, (int)(H3H / 4096));

    // 3) x = relu(inputs @ W1^T + b1)
    gemm256<true><<<dim3(16 * 8), gblk, 0, stream>>>(
        inb, W1b, b1, xb, H, IN, 16, 8);

    // 4) gi = x @ Wih^T + bih  FUSED with W2 cvt
    mega_kernel<<<dim3(16 * 24 + 2048), gblk, 0, stream>>>(
        xb, Wihb, bih, gi, 3 * H, H, 16, 24,
        W2, W2b, (int)(A2H / 4096),
        W2, W2b, 0,
        W2, W2b, 0);

    // 5) GRU -> h (fp32 into d_out, bf16 copy into hbf; Wihb is dead now)
    gru_kernel<<<dim3((Bn * H / 8) / 256), blk, 0, stream>>>(
        gi, gh, h0, hout, hbf, H);

    // 6) q = h @ W2^T + b2   (q overlays gi, which is dead after GRU)
    gemm256<false><<<dim3(16 * 16), gblk, 0, stream>>>(
        hbf, W2b, b2, q, A2, H, 16, 16);

    // 7) decode maxes -> out (fp32)
    decode_kernel<<<dim3(Bn), blk, 0, stream>>>(q, out);
}

// Round 6
// 502.059 us; speedup vs baseline: 1.1475x; 1.0567x over previous
//
#include <hip/hip_runtime.h>
#include <stdint.h>

typedef unsigned short u16;
typedef __bf16 bf16x8 __attribute__((ext_vector_type(8)));
typedef float f32x4 __attribute__((ext_vector_type(4)));
typedef u16 u16x8 __attribute__((ext_vector_type(8)));

__device__ __forceinline__ float b2f(u16 v) {
    union { float f; unsigned int u; } x; x.u = ((unsigned int)v) << 16; return x.f;
}
__device__ __forceinline__ u16 f2b(float f) {
    union { float f; unsigned int u; } x; x.f = f;
    unsigned int r = x.u + 0x7fff + ((x.u >> 16) & 1);
    return (u16)(r >> 16);
}

__device__ __forceinline__ void gll16(const void* g, void* l) {
    __builtin_amdgcn_global_load_lds(
        (const __attribute__((address_space(1))) void*)g,
        (__attribute__((address_space(3))) void*)l,
        16, 0, 0);
}

// fp32x8 -> bf16x8, round-half-up, packed via v_perm_b32.
__device__ __forceinline__ bf16x8 pack8(float4 f0, float4 f1) {
    union { float4 f; uint4 u; } a, b;
    a.f = f0; b.f = f1;
    const unsigned sel = 0x07060302u;   // D = {s0.hi16, s1.hi16}
    union { unsigned u[4]; bf16x8 v; } r;
    r.u[0] = __builtin_amdgcn_perm(a.u.y + 0x8000u, a.u.x + 0x8000u, sel);
    r.u[1] = __builtin_amdgcn_perm(a.u.w + 0x8000u, a.u.z + 0x8000u, sel);
    r.u[2] = __builtin_amdgcn_perm(b.u.y + 0x8000u, b.u.x + 0x8000u, sel);
    r.u[3] = __builtin_amdgcn_perm(b.u.w + 0x8000u, b.u.z + 0x8000u, sel);
    return r.v;
}

// cvt body: 512 thr x 8 elems = 4096 elems per block.
__device__ __forceinline__ void cvt_body(const float* __restrict__ s,
                                         u16* __restrict__ d, int cb)
{
    const size_t i = ((size_t)cb * 512 + threadIdx.x) * 8;
    float4 f0 = *(const float4*)(s + i);
    float4 f1 = *(const float4*)(s + i + 4);
    union { bf16x8 v; u16x8 u; } r;
    r.v = pack8(f0, f1);
    *(u16x8*)(d + i) = r.u;
}

// Fused 4-segment fp32->bf16 convert (h0, Whh, W1, inputs).
__global__ __launch_bounds__(512) void cvt4_kernel(
    const float* __restrict__ s0, u16* __restrict__ d0, int n0,
    const float* __restrict__ s1, u16* __restrict__ d1, int n1,
    const float* __restrict__ s2, u16* __restrict__ d2, int n2,
    const float* __restrict__ s3, u16* __restrict__ d3, int n3)
{
    int cb = blockIdx.x;
    const float* s; u16* d;
    if (cb < n0)                    { s = s0; d = d0; }
    else if ((cb -= n0) < n1)       { s = s1; d = d1; }
    else if ((cb -= n1) < n2)       { s = s2; d = d2; }
    else                            { cb -= n2; s = s3; d = d3; }
    cvt_body(s, d, cb);
}

// ===================== 256x256 8-phase GEMM body =====================
// C[M,N] = act(A[M,K] * B[N,K]^T + bias[N]), bf16 in, fp32 accum, bf16 out.
// 512 thr = 8 waves (2M x 4N), per-wave 128x64 out via interleaved strips.
// LDS: caller-provided 128 KiB = 2 K-tile buffers x 4 half-regions
// {A0,A1,B0,B1}, each [128 r][64 k] bf16, XOR-chunk-swizzled:
// phys_chunk = r*8 + (c ^ (r&7)), chunk = 8 bf16.
// NOTE: the LDS buffer is DECLARED IN THE __global__ KERNEL and passed in —
// two inlined gemm_body instantiations in one kernel would otherwise each
// get their own 128 KiB function-scope __shared__ (-> 256 KiB, compile fail).
// Sync discipline (m201): counted vmcnt waits sit BEFORE a barrier with the
// dependent ds_reads AFTER it (vmcnt is per-wave; each wave stages only a
// slice of every region). vm6 at ph3/ph7 completes the full next tile.
// XCD partition: 2x4 XCD rectangles, each (gy/2)x(gx/4) tiles -> per-XCD
// concurrent L2 footprint ~12MB. Needs gy%2==0, gx%4==0.

#define FBAR() do { asm volatile("" ::: "memory"); \
                    __builtin_amdgcn_s_barrier();  \
                    asm volatile("" ::: "memory"); } while (0)
#define WAIT_LGKM0() asm volatile("s_waitcnt lgkmcnt(0)" ::: "memory")
#define WAIT_VM6()   asm volatile("s_waitcnt vmcnt(6)" ::: "memory")
#define WAIT_VM0()   asm volatile("s_waitcnt vmcnt(0)" ::: "memory")
#define LREG(buf, idx) (Ls + ((buf) * 4 + (idx)) * 8192)

__device__ __forceinline__ void stage_half(
    const u16* __restrict__ Mp, int rowBase, int K, int k0,
    u16* region, int t, int w)
{
#pragma unroll
    for (int it = 0; it < 2; ++it) {
        const int phys = it * 512 + t;        // chunk 0..1023
        const int r = phys >> 3;              // row 0..127
        const int c = (phys & 7) ^ (r & 7);   // swizzled source k-chunk
        gll16(Mp + (size_t)(rowBase + r) * K + (k0 + c * 8),
              (char*)region + (it * 512 + w * 64) * 16);
    }
}

__device__ __forceinline__ void ld_a(const u16* region, int ra, int g0,
                                     bf16x8 (&out)[4][2])
{
#pragma unroll
    for (int mi = 0; mi < 4; ++mi)
#pragma unroll
        for (int s = 0; s < 2; ++s) {
            const int lr = mi * 32 + ra;      // ra = wr*16 + (l&15)
            out[mi][s] = *(const bf16x8*)((const char*)region +
                         (lr * 8 + ((s * 4 + g0) ^ (lr & 7))) * 16);
        }
}

__device__ __forceinline__ void ld_b(const u16* region, int rb, int g0,
                                     bf16x8 (&out)[2][2])
{
#pragma unroll
    for (int ni = 0; ni < 2; ++ni)
#pragma unroll
        for (int s = 0; s < 2; ++s) {
            const int lr = ni * 64 + rb;      // rb = wc*16 + (l&15)
            out[ni][s] = *(const bf16x8*)((const char*)region +
                         (lr * 8 + ((s * 4 + g0) ^ (lr & 7))) * 16);
        }
}

template <int MO, int NO>
__device__ __forceinline__ void mfma_quad(const bf16x8 (&af)[4][2],
                                          const bf16x8 (&bf)[2][2],
                                          f32x4 (&acc)[8][4])
{
    __builtin_amdgcn_s_setprio(1);
#pragma unroll
    for (int mi = 0; mi < 4; ++mi)
#pragma unroll
        for (int ni = 0; ni < 2; ++ni)
#pragma unroll
            for (int s = 0; s < 2; ++s)
                acc[MO + mi][NO + ni] = __builtin_amdgcn_mfma_f32_16x16x32_bf16(
                    af[mi][s], bf[ni][s], acc[MO + mi][NO + ni], 0, 0, 0);
    __builtin_amdgcn_s_setprio(0);
}

template <bool RELU>
__device__ __forceinline__ void gemm_body(
    u16* Ls,
    const u16* __restrict__ A, const u16* __restrict__ Bw,
    const float* __restrict__ bias, u16* __restrict__ C,
    int N, int K, int gy, int gx, int bid)
{
    const int t = threadIdx.x;
    const int l = t & 63;
    const int w = t >> 6;
    const int wr = w >> 2;    // 0..1
    const int wc = w & 3;     // 0..3

    // 2x4 rectangular XCD partition (bijective; needs gy%2==0, gx%4==0,
    // and gy*gx % 8 == 0). bid round-robins over XCDs (bid&7).
    const int xcd = bid & 7, rem = bid >> 3;
    const int rrows = gy >> 1, rcols = gx >> 2;
    const int lr_ = rem / rcols, lc_ = rem % rcols;
    const int mBase = ((xcd >> 2) * rrows + lr_) * 256;
    const int nBase = ((xcd & 3) * rcols + lc_) * 256;

    const int frow = l & 15;
    const int g0 = l >> 4;
    const int ra = wr * 16 + frow;
    const int rb = wc * 16 + frow;

    f32x4 acc[8][4] = {};
    bf16x8 a0[4][2], a1[4][2], b0[2][2], b1[2][2];

    const int NI = K >> 7;   // K/128; requires K multiple of 128, K >= 256

    // prologue: tile0 -> buf0 (all 4 halves first!), tile1 -> buf1 (3 halves)
    stage_half(A,  mBase,       K, 0,  LREG(0, 0), t, w);
    stage_half(Bw, nBase,       K, 0,  LREG(0, 2), t, w);
    stage_half(Bw, nBase + 128, K, 0,  LREG(0, 3), t, w);
    stage_half(A,  mBase + 128, K, 0,  LREG(0, 1), t, w);
    stage_half(A,  mBase,       K, 64, LREG(1, 0), t, w);
    stage_half(Bw, nBase,       K, 64, LREG(1, 2), t, w);
    stage_half(Bw, nBase + 128, K, 64, LREG(1, 3), t, w);
    WAIT_VM6();          // completes the 8 oldest = all of tile0 (buf0)
    FBAR();              // -> buf0 globally visible before any ph0 read

    for (int i = 0; i < NI; ++i) {
        const bool nl = (i + 1 < NI);
        const int kT1 = (2 * i + 1) << 6;
        const int kT2 = (2 * i + 2) << 6;
        const int kT3 = (2 * i + 3) << 6;

        // ---- phase 0 ----
        ld_a(LREG(0, 0), ra, g0, a0);
        ld_b(LREG(0, 2), rb, g0, b0);
        stage_half(A, mBase + 128, K, kT1, LREG(1, 1), t, w);     // (2i+1).A1
        FBAR();
        WAIT_LGKM0();
        mfma_quad<0, 0>(a0, b0, acc);
        FBAR();

        // ---- phase 1 ----
        ld_b(LREG(0, 3), rb, g0, b1);
        if (nl) stage_half(A, mBase, K, kT2, LREG(0, 0), t, w);   // (2i+2).A0
        FBAR();
        WAIT_LGKM0();
        mfma_quad<0, 2>(a0, b1, acc);
        FBAR();

        // ---- phase 2 ----
        ld_a(LREG(0, 1), ra, g0, a1);
        if (nl) stage_half(Bw, nBase, K, kT2, LREG(0, 2), t, w);  // (2i+2).B0
        FBAR();
        WAIT_LGKM0();
        mfma_quad<4, 0>(a1, b0, acc);
        FBAR();

        // ---- phase 3 ----  (wait BEFORE barrier; ph4 reads AFTER it)
        if (nl) stage_half(Bw, nBase + 128, K, kT2, LREG(0, 3), t, w); // .B1
        FBAR();
        mfma_quad<4, 2>(a1, b1, acc);
        if (nl) { WAIT_VM6(); } else { WAIT_VM0(); }
        FBAR();

        // ---- phase 4 ----
        ld_a(LREG(1, 0), ra, g0, a0);
        ld_b(LREG(1, 2), rb, g0, b0);
        if (nl) stage_half(A, mBase + 128, K, kT2, LREG(0, 1), t, w); // .A1
        FBAR();
        WAIT_LGKM0();
        mfma_quad<0, 0>(a0, b0, acc);
        FBAR();

        // ---- phase 5 ----
        ld_b(LREG(1, 3), rb, g0, b1);
        if (nl) stage_half(A, mBase, K, kT3, LREG(1, 0), t, w);   // (2i+3).A0
        FBAR();
        WAIT_LGKM0();
        mfma_quad<0, 2>(a0, b1, acc);
        FBAR();

        // ---- phase 6 ----
        ld_a(LREG(1, 1), ra, g0, a1);
        if (nl) stage_half(Bw, nBase, K, kT3, LREG(1, 2), t, w);  // (2i+3).B0
        FBAR();
        WAIT_LGKM0();
        mfma_quad<4, 0>(a1, b0, acc);
        FBAR();

        // ---- phase 7 ----  (wait BEFORE barrier; next ph0 reads AFTER it)
        if (nl) stage_half(Bw, nBase + 128, K, kT3, LREG(1, 3), t, w); // .B1
        FBAR();
        mfma_quad<4, 2>(a1, b1, acc);
        if (nl) { WAIT_VM6(); }
        FBAR();
    }

    // epilogue: C/D layout col = l&15, row = (l>>4)*4 + reg
    const int rq = (l >> 4) * 4;
#pragma unroll
    for (int ni = 0; ni < 4; ++ni) {
        const int col = nBase + ni * 64 + wc * 16 + (l & 15);
        const float bv = bias[col];
#pragma unroll
        for (int mi = 0; mi < 8; ++mi) {
            const int row = mBase + mi * 32 + wr * 16 + rq;
#pragma unroll
            for (int i2 = 0; i2 < 4; ++i2) {
                float v = acc[mi][ni][i2] + bv;
                if (RELU) v = fmaxf(v, 0.0f);
                C[(size_t)(row + i2) * N + col] = f2b(v);
            }
        }
    }
}

// Standalone GEMM launch (1-D grid of gy*gx blocks) — used for q.
template <bool RELU>
__global__ __launch_bounds__(512, 2) void gemm256(
    const u16* __restrict__ A, const u16* __restrict__ Bw,
    const float* __restrict__ bias, u16* __restrict__ C,
    int N, int K, int gy, int gx)
{
    __shared__ alignas(16) u16 L[2 * 4 * 8192];
    gemm_body<RELU>(L, A, Bw, bias, C, N, K, gy, gx, blockIdx.x);
}

// mega1: blocks [0,384) = gh GEMM (4096x6144, K=2048);
//        [384,512)      = x GEMM  (4096x2048, K=1024, ReLU) — fills gh's
//                         half-empty 2nd scheduling round;
//        [512,...)      = Wih fp32->bf16 cvt filler.
// gh and x are independent (both read only cvt4 outputs). One shared LDS
// buffer serves whichever GEMM branch this block runs.
__global__ __launch_bounds__(512, 2) void mega1_kernel(
    const u16* __restrict__ ghA, const u16* __restrict__ ghB,
    const float* __restrict__ ghBias, u16* __restrict__ ghC,
    const u16* __restrict__ xA, const u16* __restrict__ xB,
    const float* __restrict__ xBias, u16* __restrict__ xC,
    const float* __restrict__ cs, u16* __restrict__ cd)
{
    __shared__ alignas(16) u16 L[2 * 4 * 8192];
    int bid = blockIdx.x;
    if (bid < 16 * 24) {
        gemm_body<false>(L, ghA, ghB, ghBias, ghC, 6144, 2048, 16, 24, bid);
        return;
    }
    bid -= 16 * 24;
    if (bid < 16 * 8) {
        gemm_body<true>(L, xA, xB, xBias, xC, 2048, 1024, 16, 8, bid);
        return;
    }
    cvt_body(cs, cd, bid - 16 * 8);
}

// mega2: blocks [0,384) = gi GEMM (4096x6144, K=2048); rest = W2 cvt filler.
__global__ __launch_bounds__(512, 2) void mega2_kernel(
    const u16* __restrict__ A, const u16* __restrict__ Bw,
    const float* __restrict__ bias, u16* __restrict__ C,
    const float* __restrict__ cs, u16* __restrict__ cd)
{
    __shared__ alignas(16) u16 L[2 * 4 * 8192];
    int bid = blockIdx.x;
    if (bid < 16 * 24) {
        gemm_body<false>(L, A, Bw, bias, C, 6144, 2048, 16, 24, bid);
        return;
    }
    cvt_body(cs, cd, bid - 16 * 24);
}

// Fast transcendentals via hardware exp (v_exp_f32). Overflow-safe:
// sigmoid: e^{+inf} -> inf -> 1/(1+inf)=0; e^{-inf} -> 0 -> 1.
// tanh: t=e^{2|x|} -> inf -> 1-2/inf = 1, signed.
__device__ __forceinline__ float fsig(float x) {
    return 1.f / (1.f + __expf(-x));
}
__device__ __forceinline__ float ftanh(float x) {
    float t = __expf(2.f * fabsf(x));
    return copysignf(1.f - 2.f / (t + 1.f), x);
}

// GRU elementwise: r = sig(ir+hr); z = sig(iz+hz); n = tanh(inn + r*hn);
// h = (1-z)*n + z*h_prev. gi/gh bf16, hprev fp32; writes h fp32 (output) and
// bf16 copy (for the q GEMM). 8 elems/thread.
__global__ __launch_bounds__(256) void gru_kernel(
    const u16* __restrict__ gi, const u16* __restrict__ gh,
    const float* __restrict__ hprev, float* __restrict__ houtf,
    u16* __restrict__ houtb, int H)
{
    const size_t idx = ((size_t)blockIdx.x * 256 + threadIdx.x) * 8;
    const size_t b = idx / H;
    const size_t j = idx - b * H;
    const size_t g0 = b * (size_t)(3 * H) + j;

    u16x8 vir = *(const u16x8*)&gi[g0];
    u16x8 viz = *(const u16x8*)&gi[g0 + H];
    u16x8 vin = *(const u16x8*)&gi[g0 + 2 * H];
    u16x8 vhr = *(const u16x8*)&gh[g0];
    u16x8 vhz = *(const u16x8*)&gh[g0 + H];
    u16x8 vhn = *(const u16x8*)&gh[g0 + 2 * H];
    float4 hp0 = *(const float4*)&hprev[idx];
    float4 hp1 = *(const float4*)&hprev[idx + 4];
    float hp[8] = {hp0.x, hp0.y, hp0.z, hp0.w, hp1.x, hp1.y, hp1.z, hp1.w};
    float ho[8];
    u16x8 ob;
#pragma unroll
    for (int i = 0; i < 8; ++i) {
        float r = fsig(b2f(vir[i]) + b2f(vhr[i]));
        float z = fsig(b2f(viz[i]) + b2f(vhz[i]));
        float n = ftanh(b2f(vin[i]) + r * b2f(vhn[i]));
        float h = (1.f - z) * n + z * hp[i];
        ho[i] = h;
        ob[i] = f2b(h);
    }
    *(float4*)&houtf[idx]     = make_float4(ho[0], ho[1], ho[2], ho[3]);
    *(float4*)&houtf[idx + 4] = make_float4(ho[4], ho[5], ho[6], ho[7]);
    *(u16x8*)&houtb[idx] = ob;
}

// Decode: per row i of q[4096,4096] (bf16):
//   out[2i,  j] = max(q[i, j..j+63])                 (windows, j<64)
//   out[2i+1,j] = max over m with m % 64 == (j-1)%64 (strided residue class)
__global__ __launch_bounds__(256) void decode_kernel(
    const u16* __restrict__ q, float* __restrict__ out)
{
    __shared__ float s[4096];
    const int row = blockIdx.x;
    const int t = threadIdx.x;
    const size_t base = (size_t)row * 4096;
#pragma unroll
    for (int i = 0; i < 2; ++i) {
        const int j = t * 8 + i * 2048;
        u16x8 v = *(const u16x8*)&q[base + j];
#pragma unroll
        for (int k2 = 0; k2 < 8; ++k2) s[j + k2] = b2f(v[k2]);
    }
    __syncthreads();
    if (t < 64) {
        float m = -INFINITY;
#pragma unroll 8
        for (int k = 0; k < 64; ++k) m = fmaxf(m, s[t + k]);
        out[(size_t)(2 * row) * 64 + t] = m;
    } else if (t < 128) {
        const int rr = t - 64;
        float m = -INFINITY;
#pragma unroll 8
        for (int k = 0; k < 64; ++k) m = fmaxf(m, s[rr + 64 * k]);
        const int j = (rr + 1) & 63;   // residue rr corresponds to output col j
        out[(size_t)(2 * row + 1) * 64 + j] = m;
    }
}

extern "C" void kernel_launch(void* const* d_in, const int* in_sizes, int n_in,
                              void* d_out, int out_size, void* d_ws, size_t ws_size,
                              hipStream_t stream) {
    constexpr int Bn = 4096, IN = 1024, H = 2048, A = 64, A2 = A * A;
    constexpr size_t BH  = (size_t)Bn * H;        //  8,388,608
    constexpr size_t H3H = (size_t)3 * H * H;     // 12,582,912
    constexpr size_t HIN = (size_t)H * IN;        //  2,097,152
    constexpr size_t BIN = (size_t)Bn * IN;       //  4,194,304
    constexpr size_t A2H = (size_t)A2 * H;        //  8,388,608
    constexpr size_t B3H = (size_t)Bn * 3 * H;    // 25,165,824

    const float* inputs = (const float*)d_in[0];
    const float* h0     = (const float*)d_in[1];
    const float* W1     = (const float*)d_in[2];
    const float* b1     = (const float*)d_in[3];
    const float* Wih    = (const float*)d_in[4];
    const float* Whh    = (const float*)d_in[5];
    const float* bih    = (const float*)d_in[6];
    const float* bhh    = (const float*)d_in[7];
    const float* W2     = (const float*)d_in[8];
    const float* b2     = (const float*)d_in[9];

    float* out  = (float*)d_out;                 // [2B, A] fp32
    float* hout = out + (size_t)2 * Bn * A;      // [B, H] fp32 (output 1)

    // ws layout (u16 elems), non-overlapping lifetimes — peak 172.0 MB:
    //  r0 [0, B3H):       h0b [0,BH) + Whhb [BH,BH+H3H)  -> gi -> q
    //  r1 [B3H, 2B3H):    gh
    //  r2 [2B3H, +H3H):   Wihb  -> hbf (after mega2)
    //  r3..: W1b, inb, xb, W2b
    u16* wsu  = (u16*)d_ws;
    u16* h0b  = wsu;                       // cvt4 -> mega1
    u16* Whhb = wsu + BH;                  // cvt4 -> mega1
    u16* gi   = wsu;                       // mega2 -> gru (h0b/Whhb dead)
    u16* q    = wsu;                       // q GEMM -> decode (gi dead)
    u16* gh   = wsu + B3H;                 // mega1 -> gru
    u16* Wihb = wsu + 2 * B3H;             // mega1(cvt) -> mega2
    u16* hbf  = wsu + 2 * B3H;             // gru -> q GEMM (Wihb dead)
    u16* W1b  = wsu + 2 * B3H + H3H;       // cvt4 -> mega1
    u16* inb  = W1b + HIN;                 // cvt4 -> mega1
    u16* xb   = inb + BIN;                 // mega1 -> mega2
    u16* W2b  = xb + BH;                   // mega2(cvt) -> q GEMM

    dim3 blk(256);
    dim3 gblk(512);

    // L1: all GEMM-input cvts for mega1 (h0, Whh, W1, inputs) in one launch
    cvt4_kernel<<<dim3(2048 + 3072 + 512 + 1024), gblk, 0, stream>>>(
        h0, h0b, 2048, Whh, Whhb, 3072, W1, W1b, 512, inputs, inb, 1024);

    // L2: gh GEMM (384) + x GEMM (128, fills gh's half-empty round) +
    //     Wih cvt filler (3072) in gh's shadow
    mega1_kernel<<<dim3(384 + 128 + 3072), gblk, 0, stream>>>(
        h0b, Whhb, bhh, gh, inb, W1b, b1, xb, Wih, Wihb);

    // L3: gi GEMM (384) + W2 cvt filler (2048)
    mega2_kernel<<<dim3(384 + 2048), gblk, 0, stream>>>(
        xb, Wihb, bih, gi, W2, W2b);

    // L4: GRU -> h (fp32 into d_out, bf16 copy into hbf)
    gru_kernel<<<dim3((Bn * H / 8) / 256), blk, 0, stream>>>(
        gi, gh, h0, hout, hbf, H);

    // L5: q = h @ W2^T + b2  (256 blocks = exactly 1 round)
    gemm256<false><<<dim3(256), gblk, 0, stream>>>(
        hbf, W2b, b2, q, A2, H, 16, 16);

    // L6: decode maxes -> out (fp32)
    decode_kernel<<<dim3(Bn), blk, 0, stream>>>(q, out);
}